// Round 3
// baseline (264.828 us; speedup 1.0000x reference)
//
#include <hip/hip_runtime.h>
#include <math.h>

// Problem constants
#define BB    64
#define TT    512
#define TWOH  1024
#define RPW   2                  // t-rows per WAVE
#define WPB   4                  // waves per block (256 threads)
#define TCB   (RPW * WPB)        // 8 rows per block-chunk
#define NCHUNK (TT / TCB)        // 64 chunk-partials per b
#define KSPLIT 4                 // d-dim split for k_qgemm
#define NP_STRIDE ((TT + 1) * TWOH)  // 513*1024

// native clang vector type (vectorized loads/stores)
typedef float vfloat4 __attribute__((ext_vector_type(4)));

// NOTE (R3 post-mortem): __builtin_nontemporal_store on out_np caused
// post-timing divergence under the harness's re-poison path — no nt stores.
// NOTE (R1/R2 post-mortem): ANY structure where prev-row data must live in
// VGPRs between load and its two consumers (copy-store + ct-FMA) gets
// register-minimized by the allocator (VGPR 52/56/60 across 3 rewrites),
// serializing loads at ~2.7 TB/s. This version stages rows via
// global_load_lds DMA (no dest VGPRs — nothing to sink) into per-wave
// private LDS; both consumers are served by cheap ds_read_b128.

// direct global->LDS DMA, 16B per lane; lds dst is WAVE-UNIFORM base
// (HW adds lane*16), global src is per-lane.
__device__ __forceinline__ void gload_lds16(const float* g, float* l) {
    __builtin_amdgcn_global_load_lds(
        (const __attribute__((address_space(1))) unsigned int*)g,
        (__attribute__((address_space(3))) unsigned int*)l,
        16, 0, 0);
}

// -------------------------------------------------------------------------
// K1: partial GEMM  qpart[k][b][e] = sum_{d in k-slice} h[b,d] * W[d,e]
// grid = (4 e-chunks, 64 b, 4 k-slices) = 1024 blocks -> 4 blocks/CU.
// -------------------------------------------------------------------------
__global__ __launch_bounds__(256) void k_qgemm(const float* __restrict__ h,
                                               const float* __restrict__ W,
                                               float* __restrict__ qpart) {
    const int tid = threadIdx.x;
    const int e   = blockIdx.x * 256 + tid;      // 0..1023
    const int b   = blockIdx.y;                  // 0..63
    const int k   = blockIdx.z;                  // 0..3
    const int d0  = k * (TWOH / KSPLIT);         // 256-wide d slice

    __shared__ float sh[TWOH / KSPLIT];
    sh[tid] = h[b * TWOH + d0 + tid];
    __syncthreads();

    const float* __restrict__ Wp = W + (size_t)d0 * TWOH + e;
    float acc = 0.f;
    #pragma unroll 16
    for (int d = 0; d < TWOH / KSPLIT; ++d)
        acc = fmaf(sh[d], Wp[(size_t)d * TWOH], acc);

    qpart[((size_t)k * BB + b) * TWOH + e] = acc;
}

// -------------------------------------------------------------------------
// K2: DMA-staged. Per wave: 8x global_load_lds (2 rows -> private 8KB LDS
// region), one vmcnt(0) (no barrier: region is wave-private), then
//   pass A: ds_read rows -> copy-store to out_np + per-lane dot partials
//   reduce (12 shuffles) + 2-row softmax
//   pass B: ds_read rows -> ct FMA
//   combine: wave partial into own region (rows dead), 1 barrier, block
//   reduce -> one 8-row partial per block.
// LDS 32 KB -> 5 blocks/CU. grid = (NCHUNK=64, 64 b) = 4096 blocks.
// -------------------------------------------------------------------------
__global__ __launch_bounds__(256, 4) void k_scores_ct(const float* __restrict__ prev,
                                                      const float* __restrict__ qpart,
                                                      float* __restrict__ out_np,
                                                      float* __restrict__ ws_m,
                                                      float* __restrict__ ws_l,
                                                      float* __restrict__ ws_ct) {
    const int tid  = threadIdx.x;
    const int lane = tid & 63;
    const int wid  = tid >> 6;
    const int c    = blockIdx.x;                 // chunk 0..63
    const int b    = blockIdx.y;                 // 0..63
    const int t0   = c * TCB + wid * RPW;        // this wave's first row

    __shared__ float smem[WPB][RPW][TWOH];       // 32 KB, wave-private regions

    // 1) DMA this wave's rows into its LDS region (issued first, in flight
    //    under the q loads; no VGPR destinations to schedule around)
    const float* gbase = prev + ((size_t)b * TT + t0) * TWOH;
    #pragma unroll
    for (int r = 0; r < RPW; ++r)
        #pragma unroll
        for (int j = 0; j < 4; ++j)
            gload_lds16(gbase + r * TWOH + j * 256 + lane * 4, &smem[wid][r][j * 256]);

    // 2) q[b] lane-slice = sum of 4 k-partials (L2-hot)
    const vfloat4* __restrict__ qp = (const vfloat4*)qpart;
    vfloat4 q[4];
    #pragma unroll
    for (int j = 0; j < 4; ++j)
        q[j] = qp[(0 * BB + b) * 256 + j * 64 + lane]
             + qp[(1 * BB + b) * 256 + j * 64 + lane]
             + qp[(2 * BB + b) * 256 + j * 64 + lane]
             + qp[(3 * BB + b) * 256 + j * 64 + lane];

    // DMA completion is tracked by this wave's vmcnt only; no barrier needed.
    asm volatile("s_waitcnt vmcnt(0)" ::: "memory");
    __builtin_amdgcn_sched_barrier(0);

    // 3) pass A: copy-store + dot partials from LDS
    const vfloat4* srow = (const vfloat4*)&smem[wid][0][0];   // row stride 256 f4
    vfloat4* __restrict__ nprow =
        (vfloat4*)(out_np + (size_t)b * NP_STRIDE + (size_t)t0 * TWOH) + lane;
    float pd[RPW];
    #pragma unroll
    for (int r = 0; r < RPW; ++r) {
        const vfloat4 v0 = srow[r * 256 +       lane];
        const vfloat4 v1 = srow[r * 256 +  64 + lane];
        const vfloat4 v2 = srow[r * 256 + 128 + lane];
        const vfloat4 v3 = srow[r * 256 + 192 + lane];
        nprow[r * 256      ] = v0;
        nprow[r * 256 +  64] = v1;
        nprow[r * 256 + 128] = v2;
        nprow[r * 256 + 192] = v3;
        float d0 = v0.x * q[0].x; d0 = fmaf(v0.y, q[0].y, d0);
        d0 = fmaf(v0.z, q[0].z, d0); d0 = fmaf(v0.w, q[0].w, d0);
        float d1 = v1.x * q[1].x; d1 = fmaf(v1.y, q[1].y, d1);
        d1 = fmaf(v1.z, q[1].z, d1); d1 = fmaf(v1.w, q[1].w, d1);
        float d2 = v2.x * q[2].x; d2 = fmaf(v2.y, q[2].y, d2);
        d2 = fmaf(v2.z, q[2].z, d2); d2 = fmaf(v2.w, q[2].w, d2);
        float d3 = v3.x * q[3].x; d3 = fmaf(v3.y, q[3].y, d3);
        d3 = fmaf(v3.z, q[3].z, d3); d3 = fmaf(v3.w, q[3].w, d3);
        pd[r] = (d0 + d1) + (d2 + d3);
    }
    #pragma unroll
    for (int r = 0; r < RPW; ++r)
        #pragma unroll
        for (int off = 32; off > 0; off >>= 1)
            pd[r] += __shfl_xor(pd[r], off, 64);

    // wave-local softmax over RPW=2 wave-uniform scores
    const float m = fmaxf(pd[0], pd[1]);
    float a[RPW];
    float l = 0.f;
    #pragma unroll
    for (int r = 0; r < RPW; ++r) { a[r] = __expf(pd[r] - m); l += a[r]; }

    // 4) pass B: ct accumulate from LDS re-read (cheap, deterministic)
    vfloat4 ct[4];
    #pragma unroll
    for (int j = 0; j < 4; ++j) ct[j] = (vfloat4)(0.f);
    #pragma unroll
    for (int r = 0; r < RPW; ++r) {
        #pragma unroll
        for (int j = 0; j < 4; ++j) {
            const vfloat4 v = srow[r * 256 + j * 64 + lane];
            ct[j].x = fmaf(a[r], v.x, ct[j].x);
            ct[j].y = fmaf(a[r], v.y, ct[j].y);
            ct[j].z = fmaf(a[r], v.z, ct[j].z);
            ct[j].w = fmaf(a[r], v.w, ct[j].w);
        }
    }

    // 5) wave partial into own region (rows dead; program order per wave)
    float* cb = &smem[wid][0][0];                // 2048 floats; ct in [0,1024)
    #pragma unroll
    for (int j = 0; j < 4; ++j) ((vfloat4*)cb)[j * 64 + lane] = ct[j];
    if (lane == 0) { cb[TWOH] = m; cb[TWOH + 1] = l; }
    __syncthreads();

    // 6) block combine (all 256 threads; each owns float4 at index tid)
    const float* s0 = &smem[0][0][0];
    float mw[WPB], lw[WPB];
    #pragma unroll
    for (int w = 0; w < WPB; ++w) {
        mw[w] = s0[w * (RPW * TWOH) + TWOH];
        lw[w] = s0[w * (RPW * TWOH) + TWOH + 1];
    }
    const float M = fmaxf(fmaxf(mw[0], mw[1]), fmaxf(mw[2], mw[3]));
    float L = 0.f;
    vfloat4 o = (vfloat4)(0.f);
    #pragma unroll
    for (int w = 0; w < WPB; ++w) {
        const float co = __expf(mw[w] - M);
        L = fmaf(co, lw[w], L);
        const vfloat4 v = ((const vfloat4*)(s0 + w * (RPW * TWOH)))[tid];
        o.x = fmaf(co, v.x, o.x);
        o.y = fmaf(co, v.y, o.y);
        o.z = fmaf(co, v.z, o.z);
        o.w = fmaf(co, v.w, o.w);
    }
    ((vfloat4*)(ws_ct + ((size_t)b * NCHUNK + c) * TWOH))[tid] = o;
    if (tid == 0) {
        ws_m[b * NCHUNK + c] = M;
        ws_l[b * NCHUNK + c] = L;
    }
}

// -------------------------------------------------------------------------
// K3: combine NCHUNK=64 chunk partials per b; also new_prev[b,512,:] = h[b,:].
// Single fused loop: coef computed once, feeds both L and the ct accumulate.
// grid = (4 e-chunks, 64 b) = 256 blocks; thread owns one e.
// -------------------------------------------------------------------------
__global__ __launch_bounds__(256) void k_finalize(const float* __restrict__ h,
                                                  const float* __restrict__ ws_m,
                                                  const float* __restrict__ ws_l,
                                                  const float* __restrict__ ws_ct,
                                                  float* __restrict__ out_ct,
                                                  float* __restrict__ out_np) {
    const int tid = threadIdx.x;
    const int e   = blockIdx.x * 256 + tid;
    const int b   = blockIdx.y;

    const float* __restrict__ wm = ws_m + b * NCHUNK;
    const float* __restrict__ wl = ws_l + b * NCHUNK;

    float M = -INFINITY;
    #pragma unroll
    for (int i = 0; i < NCHUNK; ++i) M = fmaxf(M, wm[i]);

    const float* __restrict__ cp = ws_ct + (size_t)b * NCHUNK * TWOH + e;
    float L = 0.f;
    float acc = 0.f;
    #pragma unroll
    for (int i = 0; i < NCHUNK; ++i) {
        const float ce = __expf(wm[i] - M);
        L   = fmaf(ce, wl[i], L);
        acc = fmaf(ce, cp[(size_t)i * TWOH], acc);
    }
    out_ct[b * TWOH + e] = acc * (1.0f / L);

    // concat row: new_prev[b, T, :] = h[b, :]
    out_np[(size_t)b * NP_STRIDE + (size_t)TT * TWOH + e] = h[b * TWOH + e];
}

extern "C" void kernel_launch(void* const* d_in, const int* in_sizes, int n_in,
                              void* d_out, int out_size, void* d_ws, size_t ws_size,
                              hipStream_t stream) {
    const float* h    = (const float*)d_in[0];   // (64, 1024)
    const float* prev = (const float*)d_in[1];   // (64, 512, 1024)
    const float* W    = (const float*)d_in[2];   // (1, 1024, 1024)
    float* out    = (float*)d_out;
    float* out_ct = out;                         // (64, 1024)
    float* out_np = out + BB * TWOH;             // (64, 513, 1024)

    // ws layout (floats): qpart[4*64*1024] | m[64*64] | l[64*64] | ct[64*64*1024]
    // total ~= 17.1 MB (R1-proven size).
    float* qpart = (float*)d_ws;
    float* wsm   = qpart + KSPLIT * BB * TWOH;
    float* wsl   = wsm + BB * NCHUNK;
    float* wsc   = wsl + BB * NCHUNK;

    k_qgemm<<<dim3(4, BB, KSPLIT), 256, 0, stream>>>(h, W, qpart);
    k_scores_ct<<<dim3(NCHUNK, BB), 256, 0, stream>>>(prev, qpart, out_np, wsm, wsl, wsc);
    k_finalize<<<dim3(4, BB), 256, 0, stream>>>(h, wsm, wsl, wsc, out_ct, out_np);
}